// Round 2
// baseline (2049.297 us; speedup 1.0000x reference)
//
#include <hip/hip_runtime.h>
#include <cstdint>
#include <cstddef>

// ---- problem constants ----
#define D_IN   2048
#define STATE_N 16
#define SEQ_L  4096
#define BATCH  4
#define M_TOT  (BATCH * SEQ_L)   // 16384
#define NCAT   (3 * D_IN)        // 6144
#define LC     256               // scan chunk length
#define NCHUNK (SEQ_L / LC)      // 16

typedef __bf16 bf16x8 __attribute__((ext_vector_type(8)));
typedef float  f32x4  __attribute__((ext_vector_type(4)));
typedef unsigned int u32x4 __attribute__((ext_vector_type(4)));

__device__ __forceinline__ float softplus_f(float x) {
    return log1pf(expf(-fabsf(x))) + fmaxf(x, 0.f);
}
__device__ __forceinline__ unsigned short f2bf(float f) {  // RNE f32->bf16
    unsigned u = __float_as_uint(f);
    u += 0x7FFFu + ((u >> 16) & 1u);
    return (unsigned short)(u >> 16);
}
__device__ __forceinline__ float bf2f(unsigned short h) {
    return __uint_as_float(((unsigned)h) << 16);
}

// async global->LDS, 16B per lane (wave-uniform LDS base + lane*16 pattern)
__device__ __forceinline__ void gload_lds16(const unsigned short* g, unsigned short* l) {
    __builtin_amdgcn_global_load_lds(
        (const __attribute__((address_space(1))) unsigned int*)(const void*)g,
        (__attribute__((address_space(3))) unsigned int*)(void*)l,
        16, 0, 0);
}

// ---------------- u -> bf16 ----------------
__global__ __launch_bounds__(256) void k_cvt_u(const float* __restrict__ u,
                                               unsigned short* __restrict__ ub) {
    size_t i = ((size_t)blockIdx.x * 256 + threadIdx.x) * 8;
    f32x4 a = *(const f32x4*)(u + i);
    f32x4 b = *(const f32x4*)(u + i + 4);
    u32x4 o;
    o[0] = (unsigned)f2bf(a[0]) | ((unsigned)f2bf(a[1]) << 16);
    o[1] = (unsigned)f2bf(a[2]) | ((unsigned)f2bf(a[3]) << 16);
    o[2] = (unsigned)f2bf(b[0]) | ((unsigned)f2bf(b[1]) << 16);
    o[3] = (unsigned)f2bf(b[2]) | ((unsigned)f2bf(b[3]) << 16);
    *(u32x4*)(ub + i) = o;
}

// ---------------- W(cat) -> Wt bf16 (NCAT x K) ----------------
__global__ __launch_bounds__(256) void k_transpose(const float* __restrict__ Wdt,
                                                   const float* __restrict__ Wb,
                                                   const float* __restrict__ Wc,
                                                   unsigned short* __restrict__ Btb) {
    __shared__ float tile[32][33];
    int e0 = blockIdx.x * 32;   // column in cat space
    int k0 = blockIdx.y * 32;   // row of W
    const float* W; int eo;
    if (e0 >= 2 * D_IN)      { W = Wc; eo = e0 - 2 * D_IN; }
    else if (e0 >= D_IN)     { W = Wb; eo = e0 - D_IN; }
    else                     { W = Wdt; eo = e0; }
    int tx = threadIdx.x, ty = threadIdx.y;
#pragma unroll
    for (int i = ty; i < 32; i += 8)
        tile[i][tx] = W[(size_t)(k0 + i) * D_IN + eo + tx];
    __syncthreads();
#pragma unroll
    for (int i = ty; i < 32; i += 8)
        Btb[(size_t)(e0 + i) * D_IN + k0 + tx] = f2bf(tile[tx][i]);
}

// ---------------- fused projection GEMM ----------------
__global__ __launch_bounds__(256) void k_gemm(const unsigned short* __restrict__ Au,
                                              const unsigned short* __restrict__ Btb,
                                              const float* __restrict__ bdt,
                                              const float* __restrict__ bbv,
                                              const float* __restrict__ bcv,
                                              float* __restrict__ dtp,
                                              unsigned short* __restrict__ btp,
                                              unsigned short* __restrict__ ctp) {
    __shared__ unsigned short As[128 * 32];
    __shared__ unsigned short Bs[128 * 32];
    int bn = blockIdx.x, bm = blockIdx.y;
    int tid = threadIdx.x;
    int lane = tid & 63, wave = tid >> 6;
    int wr = wave >> 1, wc = wave & 1;
    int l15 = lane & 15, lhi = lane >> 4;

    f32x4 acc[4][4] = {};

    const int c0 = tid, c1 = tid + 256;
    const int r0 = c0 >> 2, k0off = (c0 & 3) * 8;
    const int r1 = c1 >> 2, k1off = (c1 & 3) * 8;
    const unsigned short* Ag0 = Au + (size_t)(bm * 128 + r0) * D_IN + k0off;
    const unsigned short* Ag1 = Au + (size_t)(bm * 128 + r1) * D_IN + k1off;
    const unsigned short* Bg0 = Btb + (size_t)(bn * 128 + r0) * D_IN + k0off;
    const unsigned short* Bg1 = Btb + (size_t)(bn * 128 + r1) * D_IN + k1off;

    for (int kt = 0; kt < D_IN; kt += 32) {
        __syncthreads();
        gload_lds16(Ag0 + kt, &As[c0 * 8]);
        gload_lds16(Ag1 + kt, &As[c1 * 8]);
        gload_lds16(Bg0 + kt, &Bs[c0 * 8]);
        gload_lds16(Bg1 + kt, &Bs[c1 * 8]);
        __syncthreads();
        bf16x8 af[4], bfr[4];
#pragma unroll
        for (int i = 0; i < 4; ++i)
            af[i] = *(const bf16x8*)&As[(wr * 64 + i * 16 + l15) * 32 + lhi * 8];
#pragma unroll
        for (int j = 0; j < 4; ++j)
            bfr[j] = *(const bf16x8*)&Bs[(wc * 64 + j * 16 + l15) * 32 + lhi * 8];
#pragma unroll
        for (int i = 0; i < 4; ++i)
#pragma unroll
            for (int j = 0; j < 4; ++j)
                acc[i][j] = __builtin_amdgcn_mfma_f32_16x16x32_bf16(af[i], bfr[j], acc[i][j], 0, 0, 0);
    }

    int gm0 = bm * 128 + wr * 64 + lhi * 4;
    int gn0 = bn * 128 + wc * 64 + l15;
#pragma unroll
    for (int j = 0; j < 4; ++j) {
        int gn = gn0 + j * 16;
#pragma unroll
        for (int i = 0; i < 4; ++i) {
#pragma unroll
            for (int r = 0; r < 4; ++r) {
                int gm = gm0 + i * 16 + r;
                float v = acc[i][j][r];
                if (gn < D_IN) {
                    dtp[(size_t)gm * D_IN + gn] = softplus_f(v + bdt[gn]) + 1e-4f;
                } else if (gn < 2 * D_IN) {
                    btp[(size_t)gm * D_IN + (gn - D_IN)] = f2bf(v + bbv[gn - D_IN]);
                } else {
                    ctp[(size_t)gm * D_IN + (gn - 2 * D_IN)] = f2bf(v + bcv[gn - 2 * D_IN]);
                }
            }
        }
    }
}

// ================= chunked scan =================
// Pass A: per (b,d,n,chunk) compute local_x (x0=0) and sum(dt).
__device__ __forceinline__ void load3(const unsigned short* __restrict__ ub,
                                      const float* __restrict__ dtp,
                                      const unsigned short* __restrict__ btp,
                                      size_t base, int l0,
                                      float (&U)[8], float (&T)[8], float (&Bv)[8]) {
#pragma unroll
    for (int i = 0; i < 8; ++i) {
        size_t off = base + (size_t)(l0 + i) * D_IN;
        U[i] = bf2f(ub[off]);
        T[i] = dtp[off];
        Bv[i] = bf2f(btp[off]);
    }
}
__device__ __forceinline__ void comp3(float& x, float& sdt, float A2, float Bb,
                                      const float (&U)[8], const float (&T)[8],
                                      const float (&Bv)[8]) {
#pragma unroll
    for (int i = 0; i < 8; ++i) {
        float dtv = T[i];
        float Ab = exp2f(A2 * dtv);
        x = fmaf(Ab, x, dtv * (Bv[i] * Bb) * U[i]);
        sdt += dtv;
    }
}

__global__ __launch_bounds__(256) void k_scanA(const unsigned short* __restrict__ ub,
                                               const float* __restrict__ dtp,
                                               const unsigned short* __restrict__ btp,
                                               const float* __restrict__ a_raw,
                                               const float* __restrict__ Bbp,
                                               float* __restrict__ localx,
                                               float* __restrict__ sumdt) {
    int tid = threadIdx.x;
    int n = tid & 15, ld = tid >> 4;
    int d = blockIdx.x * 16 + ld;
    int c = blockIdx.y, b = blockIdx.z;

    float A2 = -softplus_f(a_raw[d * STATE_N + n]) * 1.4426950408889634f;
    float Bb = Bbp[d * STATE_N + n];
    size_t base = ((size_t)b * SEQ_L + (size_t)c * LC) * D_IN + d;

    float x = 0.f, sdt = 0.f;
    float aU[8], aT[8], aB[8];
    float bU[8], bT[8], bB[8];

    load3(ub, dtp, btp, base, 0, aU, aT, aB);
    for (int c0 = 0; c0 < LC; c0 += 16) {
        load3(ub, dtp, btp, base, c0 + 8, bU, bT, bB);
        comp3(x, sdt, A2, Bb, aU, aT, aB);
        if (c0 + 16 < LC)
            load3(ub, dtp, btp, base, c0 + 16, aU, aT, aB);
        comp3(x, sdt, A2, Bb, bU, bT, bB);
    }
    size_t idx = ((((size_t)b * D_IN + d) * STATE_N + n) * NCHUNK) + c;
    localx[idx] = x;
    sumdt[idx] = sdt;
}

// Pass B: combine chunk summaries -> per-chunk start states + carry.
__global__ __launch_bounds__(256) void k_scanB(const float* __restrict__ localx,
                                               const float* __restrict__ sumdt,
                                               const float* __restrict__ a_raw,
                                               float* __restrict__ x0,
                                               float* __restrict__ carry) {
    int gid = blockIdx.x * 256 + threadIdx.x;   // = (b*D_IN + d)*16 + n
    int n = gid & 15;
    int d = (gid >> 4) & (D_IN - 1);
    float A2 = -softplus_f(a_raw[d * STATE_N + n]) * 1.4426950408889634f;
    float x = 0.f;
#pragma unroll
    for (int c = 0; c < NCHUNK; ++c) {
        x0[(size_t)gid * NCHUNK + c] = x;
        x = fmaf(exp2f(A2 * sumdt[(size_t)gid * NCHUNK + c]), x,
                 localx[(size_t)gid * NCHUNK + c]);
    }
    carry[gid] = x;
}

// Pass C: re-scan each chunk from its true start state, emit y.
__device__ __forceinline__ void load4(const unsigned short* __restrict__ ub,
                                      const float* __restrict__ dtp,
                                      const unsigned short* __restrict__ btp,
                                      const unsigned short* __restrict__ ctp,
                                      size_t base, int l0,
                                      float (&U)[8], float (&T)[8],
                                      float (&Bv)[8], float (&Cv)[8]) {
#pragma unroll
    for (int i = 0; i < 8; ++i) {
        size_t off = base + (size_t)(l0 + i) * D_IN;
        U[i] = bf2f(ub[off]);
        T[i] = dtp[off];
        Bv[i] = bf2f(btp[off]);
        Cv[i] = bf2f(ctp[off]);
    }
}
__device__ __forceinline__ void comp4(float& x, int n, float A2, float Bb, float Cb,
                                      float Dd, float* __restrict__ y, size_t base, int l0,
                                      const float (&U)[8], const float (&T)[8],
                                      const float (&Bv)[8], const float (&Cv)[8]) {
#pragma unroll
    for (int i = 0; i < 8; ++i) {
        float dtv = T[i], uv = U[i];
        float Ab = exp2f(A2 * dtv);
        x = fmaf(Ab, x, dtv * (Bv[i] * Bb) * uv);
        float t = Cb * x;
        t += __shfl_xor(t, 1);
        t += __shfl_xor(t, 2);
        t += __shfl_xor(t, 4);
        t += __shfl_xor(t, 8);
        if (n == 0) y[base + (size_t)(l0 + i) * D_IN] = fmaf(Dd, uv, Cv[i] * t);
    }
}

__global__ __launch_bounds__(256) void k_scanC(const unsigned short* __restrict__ ub,
                                               const float* __restrict__ dtp,
                                               const unsigned short* __restrict__ btp,
                                               const unsigned short* __restrict__ ctp,
                                               const float* __restrict__ a_raw,
                                               const float* __restrict__ Bbp,
                                               const float* __restrict__ Cbp,
                                               const float* __restrict__ Dv,
                                               const float* __restrict__ x0,
                                               float* __restrict__ y) {
    int tid = threadIdx.x;
    int n = tid & 15, ld = tid >> 4;
    int d = blockIdx.x * 16 + ld;
    int c = blockIdx.y, b = blockIdx.z;

    float A2 = -softplus_f(a_raw[d * STATE_N + n]) * 1.4426950408889634f;
    float Bb = Bbp[d * STATE_N + n];
    float Cb = Cbp[d * STATE_N + n];
    float Dd = Dv[d];
    size_t base = ((size_t)b * SEQ_L + (size_t)c * LC) * D_IN + d;
    size_t idx = ((((size_t)b * D_IN + d) * STATE_N + n) * NCHUNK) + c;

    float x = x0[idx];
    float aU[8], aT[8], aB[8], aC[8];
    float bU[8], bT[8], bB[8], bC[8];

    load4(ub, dtp, btp, ctp, base, 0, aU, aT, aB, aC);
    for (int c0 = 0; c0 < LC; c0 += 16) {
        load4(ub, dtp, btp, ctp, base, c0 + 8, bU, bT, bB, bC);
        comp4(x, n, A2, Bb, Cb, Dd, y, base, c0, aU, aT, aB, aC);
        if (c0 + 16 < LC)
            load4(ub, dtp, btp, ctp, base, c0 + 16, aU, aT, aB, aC);
        comp4(x, n, A2, Bb, Cb, Dd, y, base, c0 + 8, bU, bT, bB, bC);
    }
}

// ---------------- launch ----------------
extern "C" void kernel_launch(void* const* d_in, const int* in_sizes, int n_in,
                              void* d_out, int out_size, void* d_ws, size_t ws_size,
                              hipStream_t stream) {
    const float* u     = (const float*)d_in[0];
    const float* Wdt   = (const float*)d_in[1];
    const float* bdt   = (const float*)d_in[2];
    const float* Wb    = (const float*)d_in[3];
    const float* bb    = (const float*)d_in[4];
    const float* Wc    = (const float*)d_in[5];
    const float* bc    = (const float*)d_in[6];
    const float* a_raw = (const float*)d_in[7];
    const float* Bbp   = (const float*)d_in[8];
    const float* Cbp   = (const float*)d_in[9];
    const float* Dv    = (const float*)d_in[10];

    float* out = (float*)d_out;
    float* carry = out;                                      // (B, d, N)
    float* y = out + (size_t)BATCH * D_IN * STATE_N;         // (B, L, d)

    const size_t Mel = (size_t)M_TOT * D_IN;                 // 33.5M elements
    const size_t Sel = (size_t)BATCH * D_IN * STATE_N * NCHUNK;  // 2.1M elements
    char* ws = (char*)d_ws;
    unsigned short* ub  = (unsigned short*)ws;                          // Mel*2
    unsigned short* Btb = (unsigned short*)(ws + Mel * 2);              // NCAT*D_IN*2
    char* p = ws + Mel * 2 + (size_t)NCAT * D_IN * 2;
    float* dtp = (float*)p;                                             // Mel*4
    unsigned short* btp = (unsigned short*)(p + Mel * 4);               // Mel*2
    unsigned short* ctp = (unsigned short*)(p + Mel * 4 + Mel * 2);     // Mel*2
    char* q = p + Mel * 4 + Mel * 2 + Mel * 2;
    float* localx = (float*)q;                                          // Sel*4
    float* sumdt  = (float*)(q + Sel * 4);                              // Sel*4
    float* x0v    = (float*)(q + Sel * 8);                              // Sel*4

    k_cvt_u<<<dim3((M_TOT * D_IN) / (256 * 8)), dim3(256), 0, stream>>>(u, ub);
    k_transpose<<<dim3(NCAT / 32, D_IN / 32), dim3(32, 8), 0, stream>>>(Wdt, Wb, Wc, Btb);
    k_gemm<<<dim3(NCAT / 128, M_TOT / 128), dim3(256), 0, stream>>>(ub, Btb, bdt, bb, bc,
                                                                    dtp, btp, ctp);
    k_scanA<<<dim3(D_IN / 16, NCHUNK, BATCH), dim3(256), 0, stream>>>(ub, dtp, btp, a_raw,
                                                                      Bbp, localx, sumdt);
    k_scanB<<<dim3((BATCH * D_IN * STATE_N) / 256), dim3(256), 0, stream>>>(localx, sumdt,
                                                                            a_raw, x0v, carry);
    k_scanC<<<dim3(D_IN / 16, NCHUNK, BATCH), dim3(256), 0, stream>>>(ub, dtp, btp, ctp,
                                                                      a_raw, Bbp, Cbp, Dv,
                                                                      x0v, y);
}

// Round 3
// 1324.397 us; speedup vs baseline: 1.5473x; 1.5473x over previous
//
#include <hip/hip_runtime.h>
#include <cstdint>
#include <cstddef>

// ---- problem constants ----
#define D_IN   2048
#define STATE_N 16
#define SEQ_L  4096
#define BATCH  4
#define M_TOT  (BATCH * SEQ_L)   // 16384
#define NCAT   (3 * D_IN)        // 6144
#define LC     128               // scan chunk length
#define NCHUNK (SEQ_L / LC)      // 32
#define BDN    (BATCH * D_IN * STATE_N)  // 131072
#define BD     (BATCH * D_IN)            // 8192

typedef __bf16 bf16x8 __attribute__((ext_vector_type(8)));
typedef float  f32x4  __attribute__((ext_vector_type(4)));
typedef unsigned int u32x4 __attribute__((ext_vector_type(4)));

__device__ __forceinline__ float softplus_f(float x) {
    return log1pf(expf(-fabsf(x))) + fmaxf(x, 0.f);
}
__device__ __forceinline__ unsigned short f2bf(float f) {  // RNE f32->bf16
    unsigned u = __float_as_uint(f);
    u += 0x7FFFu + ((u >> 16) & 1u);
    return (unsigned short)(u >> 16);
}
__device__ __forceinline__ float bf2f(unsigned short h) {
    return __uint_as_float(((unsigned)h) << 16);
}

// async global->LDS, 16B per lane (wave-uniform LDS base + lane*16 pattern)
__device__ __forceinline__ void gload_lds16(const unsigned short* g, unsigned short* l) {
    __builtin_amdgcn_global_load_lds(
        (const __attribute__((address_space(1))) unsigned int*)(const void*)g,
        (__attribute__((address_space(3))) unsigned int*)(void*)l,
        16, 0, 0);
}

// ---------------- u -> bf16 ----------------
__global__ __launch_bounds__(256) void k_cvt_u(const float* __restrict__ u,
                                               unsigned short* __restrict__ ub) {
    size_t i = ((size_t)blockIdx.x * 256 + threadIdx.x) * 8;
    f32x4 a = *(const f32x4*)(u + i);
    f32x4 b = *(const f32x4*)(u + i + 4);
    u32x4 o;
    o[0] = (unsigned)f2bf(a[0]) | ((unsigned)f2bf(a[1]) << 16);
    o[1] = (unsigned)f2bf(a[2]) | ((unsigned)f2bf(a[3]) << 16);
    o[2] = (unsigned)f2bf(b[0]) | ((unsigned)f2bf(b[1]) << 16);
    o[3] = (unsigned)f2bf(b[2]) | ((unsigned)f2bf(b[3]) << 16);
    *(u32x4*)(ub + i) = o;
}

// ---------------- W(cat) -> Wt bf16 (NCAT x K) ----------------
__global__ __launch_bounds__(256) void k_transpose(const float* __restrict__ Wdt,
                                                   const float* __restrict__ Wb,
                                                   const float* __restrict__ Wc,
                                                   unsigned short* __restrict__ Btb) {
    __shared__ float tile[32][33];
    int e0 = blockIdx.x * 32;   // column in cat space
    int k0 = blockIdx.y * 32;   // row of W
    const float* W; int eo;
    if (e0 >= 2 * D_IN)      { W = Wc; eo = e0 - 2 * D_IN; }
    else if (e0 >= D_IN)     { W = Wb; eo = e0 - D_IN; }
    else                     { W = Wdt; eo = e0; }
    int tx = threadIdx.x, ty = threadIdx.y;
#pragma unroll
    for (int i = ty; i < 32; i += 8)
        tile[i][tx] = W[(size_t)(k0 + i) * D_IN + eo + tx];
    __syncthreads();
#pragma unroll
    for (int i = ty; i < 32; i += 8)
        Btb[(size_t)(e0 + i) * D_IN + k0 + tx] = f2bf(tile[tx][i]);
}

// ---------------- fused projection GEMM ----------------
__global__ __launch_bounds__(256) void k_gemm(const unsigned short* __restrict__ Au,
                                              const unsigned short* __restrict__ Btb,
                                              const float* __restrict__ bdt,
                                              const float* __restrict__ bbv,
                                              const float* __restrict__ bcv,
                                              float* __restrict__ dtp,
                                              unsigned short* __restrict__ btp,
                                              unsigned short* __restrict__ ctp) {
    __shared__ unsigned short As[128 * 32];
    __shared__ unsigned short Bs[128 * 32];
    // T1 XCD-aware swizzle: nwg = 48*128 = 6144, divisible by 8.
    int flat = blockIdx.y * gridDim.x + blockIdx.x;
    int swz = (flat & 7) * ((48 * 128) / 8) + (flat >> 3);
    int bn = swz % 48, bm = swz / 48;
    int tid = threadIdx.x;
    int lane = tid & 63, wave = tid >> 6;
    int wr = wave >> 1, wc = wave & 1;
    int l15 = lane & 15, lhi = lane >> 4;

    f32x4 acc[4][4] = {};

    const int c0 = tid, c1 = tid + 256;
    const int r0 = c0 >> 2, k0off = (c0 & 3) * 8;
    const int r1 = c1 >> 2, k1off = (c1 & 3) * 8;
    const unsigned short* Ag0 = Au + (size_t)(bm * 128 + r0) * D_IN + k0off;
    const unsigned short* Ag1 = Au + (size_t)(bm * 128 + r1) * D_IN + k1off;
    const unsigned short* Bg0 = Btb + (size_t)(bn * 128 + r0) * D_IN + k0off;
    const unsigned short* Bg1 = Btb + (size_t)(bn * 128 + r1) * D_IN + k1off;

    for (int kt = 0; kt < D_IN; kt += 32) {
        __syncthreads();
        gload_lds16(Ag0 + kt, &As[c0 * 8]);
        gload_lds16(Ag1 + kt, &As[c1 * 8]);
        gload_lds16(Bg0 + kt, &Bs[c0 * 8]);
        gload_lds16(Bg1 + kt, &Bs[c1 * 8]);
        __syncthreads();
        bf16x8 af[4], bfr[4];
#pragma unroll
        for (int i = 0; i < 4; ++i)
            af[i] = *(const bf16x8*)&As[(wr * 64 + i * 16 + l15) * 32 + lhi * 8];
#pragma unroll
        for (int j = 0; j < 4; ++j)
            bfr[j] = *(const bf16x8*)&Bs[(wc * 64 + j * 16 + l15) * 32 + lhi * 8];
#pragma unroll
        for (int i = 0; i < 4; ++i)
#pragma unroll
            for (int j = 0; j < 4; ++j)
                acc[i][j] = __builtin_amdgcn_mfma_f32_16x16x32_bf16(af[i], bfr[j], acc[i][j], 0, 0, 0);
    }

    int gm0 = bm * 128 + wr * 64 + lhi * 4;
    int gn0 = bn * 128 + wc * 64 + l15;
#pragma unroll
    for (int j = 0; j < 4; ++j) {
        int gn = gn0 + j * 16;
#pragma unroll
        for (int i = 0; i < 4; ++i) {
#pragma unroll
            for (int r = 0; r < 4; ++r) {
                int gm = gm0 + i * 16 + r;
                float v = acc[i][j][r];
                if (gn < D_IN) {
                    dtp[(size_t)gm * D_IN + gn] = softplus_f(v + bdt[gn]) + 1e-4f;
                } else if (gn < 2 * D_IN) {
                    btp[(size_t)gm * D_IN + (gn - D_IN)] = f2bf(v + bbv[gn - D_IN]);
                } else {
                    ctp[(size_t)gm * D_IN + (gn - 2 * D_IN)] = f2bf(v + bcv[gn - 2 * D_IN]);
                }
            }
        }
    }
}

// ================= chunked scan, lane = d =================
// thread = (b, chunk, d); all 16 n-states in registers; every global access
// is coalesced across lanes (consecutive d); zero cross-lane ops.

__device__ __forceinline__ void loadA4(const unsigned short* __restrict__ ub,
                                       const float* __restrict__ dtp,
                                       const unsigned short* __restrict__ btp,
                                       size_t base, int l0,
                                       float (&T)[4], float (&U)[4], float (&Bv)[4]) {
#pragma unroll
    for (int i = 0; i < 4; ++i) {
        size_t off = base + (size_t)(l0 + i) * D_IN;
        T[i] = dtp[off];
        U[i] = bf2f(ub[off]);
        Bv[i] = bf2f(btp[off]);
    }
}

__device__ __forceinline__ void compA4(float (&x)[16], float& sdt,
                                       const float (&A2)[16], const float (&Bb)[16],
                                       const float (&T)[4], const float (&U)[4],
                                       const float (&Bv)[4]) {
#pragma unroll
    for (int i = 0; i < 4; ++i) {
        float dtv = T[i];
        float s = dtv * Bv[i] * U[i];
        sdt += dtv;
#pragma unroll
        for (int n = 0; n < 16; ++n)
            x[n] = fmaf(exp2f(A2[n] * dtv), x[n], s * Bb[n]);
    }
}

__global__ __launch_bounds__(256) void k_scanA(const unsigned short* __restrict__ ub,
                                               const float* __restrict__ dtp,
                                               const unsigned short* __restrict__ btp,
                                               const float* __restrict__ a_raw,
                                               const float* __restrict__ Bbp,
                                               float* __restrict__ localx,
                                               float* __restrict__ sumdt) {
    int tid = threadIdx.x;
    int d = blockIdx.x * 256 + tid;
    int c = blockIdx.y, b = blockIdx.z;
    const float L2E = 1.4426950408889634f;

    float A2[16], Bb[16];
#pragma unroll
    for (int n = 0; n < 16; n += 4) {
        f32x4 a = *(const f32x4*)(a_raw + d * STATE_N + n);
        f32x4 bv = *(const f32x4*)(Bbp + d * STATE_N + n);
#pragma unroll
        for (int j = 0; j < 4; ++j) {
            A2[n + j] = -softplus_f(a[j]) * L2E;
            Bb[n + j] = bv[j];
        }
    }

    size_t base = ((size_t)b * SEQ_L + (size_t)c * LC) * D_IN + d;
    float x[16];
#pragma unroll
    for (int n = 0; n < 16; ++n) x[n] = 0.f;
    float sdt = 0.f;

    float tA[4], uA[4], bA[4], tB[4], uB[4], bB[4];
    loadA4(ub, dtp, btp, base, 0, tA, uA, bA);
    for (int l0 = 0; l0 < LC; l0 += 8) {
        loadA4(ub, dtp, btp, base, l0 + 4, tB, uB, bB);
        compA4(x, sdt, A2, Bb, tA, uA, bA);
        if (l0 + 8 < LC)
            loadA4(ub, dtp, btp, base, l0 + 8, tA, uA, bA);
        compA4(x, sdt, A2, Bb, tB, uB, bB);
    }

    size_t sb = (size_t)c * BDN + ((size_t)b * D_IN + d) * STATE_N;
#pragma unroll
    for (int n = 0; n < 16; n += 4) {
        f32x4 v; v[0] = x[n]; v[1] = x[n + 1]; v[2] = x[n + 2]; v[3] = x[n + 3];
        *(f32x4*)(localx + sb + n) = v;
    }
    sumdt[(size_t)c * BD + (size_t)b * D_IN + d] = sdt;
}

// Pass B: combine chunk summaries -> per-chunk start states + carry.
__global__ __launch_bounds__(256) void k_scanB(const float* __restrict__ localx,
                                               const float* __restrict__ sumdt,
                                               const float* __restrict__ a_raw,
                                               float* __restrict__ x0,
                                               float* __restrict__ carry) {
    int gid = blockIdx.x * 256 + threadIdx.x;   // = (b*D_IN + d)*16 + n
    int n = gid & 15;
    int d = (gid >> 4) & (D_IN - 1);
    int bd = gid >> 4;
    float A2 = -softplus_f(a_raw[d * STATE_N + n]) * 1.4426950408889634f;
    float x = 0.f;
    for (int c = 0; c < NCHUNK; ++c) {
        x0[(size_t)c * BDN + gid] = x;
        float sdt = sumdt[(size_t)c * BD + bd];
        x = fmaf(exp2f(A2 * sdt), x, localx[(size_t)c * BDN + gid]);
    }
    carry[gid] = x;
}

// Pass C: re-scan each chunk from its true start state, emit y.
__device__ __forceinline__ void loadC4(const unsigned short* __restrict__ ub,
                                       const float* __restrict__ dtp,
                                       const unsigned short* __restrict__ btp,
                                       const unsigned short* __restrict__ ctp,
                                       size_t base, int l0,
                                       float (&T)[4], float (&U)[4],
                                       float (&Bv)[4], float (&Cv)[4]) {
#pragma unroll
    for (int i = 0; i < 4; ++i) {
        size_t off = base + (size_t)(l0 + i) * D_IN;
        T[i] = dtp[off];
        U[i] = bf2f(ub[off]);
        Bv[i] = bf2f(btp[off]);
        Cv[i] = bf2f(ctp[off]);
    }
}

__device__ __forceinline__ void compC4(float (&x)[16],
                                       const float (&A2)[16], const float (&Bb)[16],
                                       const float (&Cb)[16], float Dd,
                                       float* __restrict__ y, size_t base, int l0,
                                       const float (&T)[4], const float (&U)[4],
                                       const float (&Bv)[4], const float (&Cv)[4]) {
#pragma unroll
    for (int i = 0; i < 4; ++i) {
        float dtv = T[i], uv = U[i];
        float s = dtv * Bv[i] * uv;
        float y0 = 0.f, y1 = 0.f, y2 = 0.f, y3 = 0.f;
#pragma unroll
        for (int n = 0; n < 16; n += 4) {
            x[n]     = fmaf(exp2f(A2[n] * dtv),     x[n],     s * Bb[n]);
            y0 = fmaf(Cb[n], x[n], y0);
            x[n + 1] = fmaf(exp2f(A2[n + 1] * dtv), x[n + 1], s * Bb[n + 1]);
            y1 = fmaf(Cb[n + 1], x[n + 1], y1);
            x[n + 2] = fmaf(exp2f(A2[n + 2] * dtv), x[n + 2], s * Bb[n + 2]);
            y2 = fmaf(Cb[n + 2], x[n + 2], y2);
            x[n + 3] = fmaf(exp2f(A2[n + 3] * dtv), x[n + 3], s * Bb[n + 3]);
            y3 = fmaf(Cb[n + 3], x[n + 3], y3);
        }
        y[base + (size_t)(l0 + i) * D_IN] = fmaf(Dd, uv, Cv[i] * ((y0 + y1) + (y2 + y3)));
    }
}

__global__ __launch_bounds__(256) void k_scanC(const unsigned short* __restrict__ ub,
                                               const float* __restrict__ dtp,
                                               const unsigned short* __restrict__ btp,
                                               const unsigned short* __restrict__ ctp,
                                               const float* __restrict__ a_raw,
                                               const float* __restrict__ Bbp,
                                               const float* __restrict__ Cbp,
                                               const float* __restrict__ Dv,
                                               const float* __restrict__ x0,
                                               float* __restrict__ y) {
    int tid = threadIdx.x;
    int d = blockIdx.x * 256 + tid;
    int c = blockIdx.y, b = blockIdx.z;
    const float L2E = 1.4426950408889634f;

    float A2[16], Bb[16], Cb[16];
#pragma unroll
    for (int n = 0; n < 16; n += 4) {
        f32x4 a = *(const f32x4*)(a_raw + d * STATE_N + n);
        f32x4 bv = *(const f32x4*)(Bbp + d * STATE_N + n);
        f32x4 cv = *(const f32x4*)(Cbp + d * STATE_N + n);
#pragma unroll
        for (int j = 0; j < 4; ++j) {
            A2[n + j] = -softplus_f(a[j]) * L2E;
            Bb[n + j] = bv[j];
            Cb[n + j] = cv[j];
        }
    }
    float Dd = Dv[d];

    float x[16];
    size_t xb = (size_t)c * BDN + ((size_t)b * D_IN + d) * STATE_N;
#pragma unroll
    for (int n = 0; n < 16; n += 4) {
        f32x4 v = *(const f32x4*)(x0 + xb + n);
        x[n] = v[0]; x[n + 1] = v[1]; x[n + 2] = v[2]; x[n + 3] = v[3];
    }

    size_t base = ((size_t)b * SEQ_L + (size_t)c * LC) * D_IN + d;
    float tA[4], uA[4], bA[4], cA[4], tB[4], uB[4], bB[4], cB[4];
    loadC4(ub, dtp, btp, ctp, base, 0, tA, uA, bA, cA);
    for (int l0 = 0; l0 < LC; l0 += 8) {
        loadC4(ub, dtp, btp, ctp, base, l0 + 4, tB, uB, bB, cB);
        compC4(x, A2, Bb, Cb, Dd, y, base, l0, tA, uA, bA, cA);
        if (l0 + 8 < LC)
            loadC4(ub, dtp, btp, ctp, base, l0 + 8, tA, uA, bA, cA);
        compC4(x, A2, Bb, Cb, Dd, y, base, l0 + 4, tB, uB, bB, cB);
    }
}

// ---------------- launch ----------------
extern "C" void kernel_launch(void* const* d_in, const int* in_sizes, int n_in,
                              void* d_out, int out_size, void* d_ws, size_t ws_size,
                              hipStream_t stream) {
    const float* u     = (const float*)d_in[0];
    const float* Wdt   = (const float*)d_in[1];
    const float* bdt   = (const float*)d_in[2];
    const float* Wb    = (const float*)d_in[3];
    const float* bb    = (const float*)d_in[4];
    const float* Wc    = (const float*)d_in[5];
    const float* bc    = (const float*)d_in[6];
    const float* a_raw = (const float*)d_in[7];
    const float* Bbp   = (const float*)d_in[8];
    const float* Cbp   = (const float*)d_in[9];
    const float* Dv    = (const float*)d_in[10];

    float* out = (float*)d_out;
    float* carry = out;                                      // (B, d, N)
    float* y = out + (size_t)BATCH * D_IN * STATE_N;         // (B, L, d)

    const size_t Mel = (size_t)M_TOT * D_IN;                 // 33.5M elements
    char* ws = (char*)d_ws;
    unsigned short* ub  = (unsigned short*)ws;                          // Mel*2
    unsigned short* Btb = (unsigned short*)(ws + Mel * 2);              // NCAT*D_IN*2
    char* p = ws + Mel * 2 + (size_t)NCAT * D_IN * 2;
    float* dtp = (float*)p;                                             // Mel*4
    unsigned short* btp = (unsigned short*)(p + Mel * 4);               // Mel*2
    unsigned short* ctp = (unsigned short*)(p + Mel * 4 + Mel * 2);     // Mel*2
    char* q = p + Mel * 4 + Mel * 2 + Mel * 2;
    float* localx = (float*)q;                                          // NCHUNK*BDN*4
    float* x0v    = (float*)(q + (size_t)NCHUNK * BDN * 4);             // NCHUNK*BDN*4
    float* sumdt  = (float*)(q + (size_t)NCHUNK * BDN * 8);             // NCHUNK*BD*4

    k_cvt_u<<<dim3((M_TOT * D_IN) / (256 * 8)), dim3(256), 0, stream>>>(u, ub);
    k_transpose<<<dim3(NCAT / 32, D_IN / 32), dim3(32, 8), 0, stream>>>(Wdt, Wb, Wc, Btb);
    k_gemm<<<dim3(NCAT / 128, M_TOT / 128), dim3(256), 0, stream>>>(ub, Btb, bdt, bb, bc,
                                                                    dtp, btp, ctp);
    k_scanA<<<dim3(D_IN / 256, NCHUNK, BATCH), dim3(256), 0, stream>>>(ub, dtp, btp, a_raw,
                                                                       Bbp, localx, sumdt);
    k_scanB<<<dim3(BDN / 256), dim3(256), 0, stream>>>(localx, sumdt, a_raw, x0v, carry);
    k_scanC<<<dim3(D_IN / 256, NCHUNK, BATCH), dim3(256), 0, stream>>>(ub, dtp, btp, ctp,
                                                                       a_raw, Bbp, Cbp, Dv,
                                                                       x0v, y);
}

// Round 4
// 1177.567 us; speedup vs baseline: 1.7403x; 1.1247x over previous
//
#include <hip/hip_runtime.h>
#include <cstdint>
#include <cstddef>

// ---- problem constants ----
#define D_IN   2048
#define STATE_N 16
#define SEQ_L  4096
#define BATCH  4
#define M_TOT  (BATCH * SEQ_L)   // 16384
#define NCAT   (3 * D_IN)        // 6144
#define LC     128               // scan chunk length
#define NCHUNK (SEQ_L / LC)      // 32
#define BDN    (BATCH * D_IN * STATE_N)  // 131072
#define BD     (BATCH * D_IN)            // 8192

// GEMM tile params (256x256 tile, BK=32, 4-slot LDS ring)
#define BK     32
#define NT     (D_IN / BK)       // 64 K-tiles
#define SLOT_E (256 * BK)        // 8192 elements per slot per matrix

typedef __bf16 bf16x8 __attribute__((ext_vector_type(8)));
typedef float  f32x4  __attribute__((ext_vector_type(4)));
typedef unsigned int u32x4 __attribute__((ext_vector_type(4)));

__device__ __forceinline__ float softplus_f(float x) {
    return log1pf(expf(-fabsf(x))) + fmaxf(x, 0.f);
}
__device__ __forceinline__ unsigned short f2bf(float f) {  // RNE f32->bf16
    unsigned u = __float_as_uint(f);
    u += 0x7FFFu + ((u >> 16) & 1u);
    return (unsigned short)(u >> 16);
}
__device__ __forceinline__ float bf2f(unsigned short h) {
    return __uint_as_float(((unsigned)h) << 16);
}

// async global->LDS, 16B per lane (wave-uniform LDS base + lane*16 pattern)
__device__ __forceinline__ void gload_lds16(const unsigned short* g, unsigned short* l) {
    __builtin_amdgcn_global_load_lds(
        (const __attribute__((address_space(1))) unsigned int*)(const void*)g,
        (__attribute__((address_space(3))) unsigned int*)(void*)l,
        16, 0, 0);
}

// ---------------- u -> bf16 ----------------
__global__ __launch_bounds__(256) void k_cvt_u(const float* __restrict__ u,
                                               unsigned short* __restrict__ ub) {
    size_t i = ((size_t)blockIdx.x * 256 + threadIdx.x) * 8;
    f32x4 a = *(const f32x4*)(u + i);
    f32x4 b = *(const f32x4*)(u + i + 4);
    u32x4 o;
    o[0] = (unsigned)f2bf(a[0]) | ((unsigned)f2bf(a[1]) << 16);
    o[1] = (unsigned)f2bf(a[2]) | ((unsigned)f2bf(a[3]) << 16);
    o[2] = (unsigned)f2bf(b[0]) | ((unsigned)f2bf(b[1]) << 16);
    o[3] = (unsigned)f2bf(b[2]) | ((unsigned)f2bf(b[3]) << 16);
    *(u32x4*)(ub + i) = o;
}

// ---------------- W(cat) -> Wt bf16 (NCAT x K) ----------------
__global__ __launch_bounds__(256) void k_transpose(const float* __restrict__ Wdt,
                                                   const float* __restrict__ Wb,
                                                   const float* __restrict__ Wc,
                                                   unsigned short* __restrict__ Btb) {
    __shared__ float tile[32][33];
    int e0 = blockIdx.x * 32;   // column in cat space
    int k0 = blockIdx.y * 32;   // row of W
    const float* W; int eo;
    if (e0 >= 2 * D_IN)      { W = Wc; eo = e0 - 2 * D_IN; }
    else if (e0 >= D_IN)     { W = Wb; eo = e0 - D_IN; }
    else                     { W = Wdt; eo = e0; }
    int tx = threadIdx.x, ty = threadIdx.y;
#pragma unroll
    for (int i = ty; i < 32; i += 8)
        tile[i][tx] = W[(size_t)(k0 + i) * D_IN + eo + tx];
    __syncthreads();
#pragma unroll
    for (int i = ty; i < 32; i += 8)
        Btb[(size_t)(e0 + i) * D_IN + k0 + tx] = f2bf(tile[tx][i]);
}

// ---------------- fused projection GEMM: 256x256 tile, 8-wave, 4-slot ring ----------------
// Stage one K-tile half (A or B): 2 x global_load_lds, 512 threads x 16B.
// LDS layout: [256 rows][4 slots of 16B], slot XOR-swizzled by ((row>>1)&3)
// (T2, both-sides: linear LDS dest + pre-swizzled global source).
__device__ __forceinline__ void stage2(const unsigned short* __restrict__ gbase, int kt,
                                       unsigned short* lds, int tid) {
    int swz = ((((tid >> 3) & 3) ^ (tid & 3)) * 8);
#pragma unroll
    for (int h = 0; h < 2; ++h) {
        int row = h * 128 + (tid >> 2);
        gload_lds16(gbase + (size_t)row * D_IN + kt + swz, lds + h * 4096 + tid * 8);
    }
}

__global__ __launch_bounds__(512, 2) void k_gemm(const unsigned short* __restrict__ Au,
                                                 const unsigned short* __restrict__ Btb,
                                                 const float* __restrict__ bdt,
                                                 const float* __restrict__ bbv,
                                                 const float* __restrict__ bcv,
                                                 float* __restrict__ dtp,
                                                 unsigned short* __restrict__ btp,
                                                 unsigned short* __restrict__ ctp) {
    __shared__ unsigned short As[4 * SLOT_E];   // 64 KiB
    __shared__ unsigned short Bs[4 * SLOT_E];   // 64 KiB

    int tid = threadIdx.x;
    int lane = tid & 63, wave = tid >> 6;
    int wr = wave >> 1;          // 0..3  (M: 64-row slice)
    int wc = wave & 1;           // 0..1  (N: 128-col slice)
    int l15 = lane & 15, lhi = lane >> 4;

    // XCD-aware bijective swizzle: nwg = 1536 = 8*192; bn-fast for A-panel L2 reuse
    int flat = blockIdx.x;
    int swzb = (flat & 7) * 192 + (flat >> 3);
    int bm = swzb / 24, bn = swzb % 24;

    const unsigned short* Ag = Au + (size_t)(bm * 256) * D_IN;
    const unsigned short* Bg = Btb + (size_t)(bn * 256) * D_IN;

    f32x4 acc[4][8] = {};

    // ds_read element offsets (relative to slot base); T2 swizzled slot
    int swzr = (lhi ^ ((l15 >> 1) & 3)) * 8;
    int aoff = (wr * 64 + l15) * BK + swzr;
    int boff = (wc * 128 + l15) * BK + swzr;

    // ---- prologue: stage tiles 0,1,2 (12 loads), wait tile 0 ----
#pragma unroll
    for (int s = 0; s < 3; ++s) {
        stage2(Ag, s * BK, &As[s * SLOT_E], tid);
        stage2(Bg, s * BK, &Bs[s * SLOT_E], tid);
    }
    asm volatile("s_waitcnt vmcnt(8)" ::: "memory");
    __builtin_amdgcn_s_barrier();
    __builtin_amdgcn_sched_barrier(0);

    for (int t = 0; t < NT; ++t) {
        const unsigned short* asx = &As[(t & 3) * SLOT_E];
        const unsigned short* bsx = &Bs[(t & 3) * SLOT_E];
        bf16x8 af[4], bf0[4], bf1[4];

        // ---- phase 0: read A(all) + B(j0..3); stage A of tile t+3; MFMA j0..3 ----
#pragma unroll
        for (int i = 0; i < 4; ++i)
            af[i] = *(const bf16x8*)&asx[aoff + i * 16 * BK];
#pragma unroll
        for (int j = 0; j < 4; ++j)
            bf0[j] = *(const bf16x8*)&bsx[boff + j * 16 * BK];
        if (t + 3 < NT)
            stage2(Ag, (t + 3) * BK, &As[((t + 3) & 3) * SLOT_E], tid);
        __builtin_amdgcn_s_barrier();
        __builtin_amdgcn_sched_barrier(0);
        __builtin_amdgcn_s_setprio(1);
#pragma unroll
        for (int i = 0; i < 4; ++i)
#pragma unroll
            for (int j = 0; j < 4; ++j)
                acc[i][j] = __builtin_amdgcn_mfma_f32_16x16x32_bf16(af[i], bf0[j], acc[i][j], 0, 0, 0);
        __builtin_amdgcn_s_setprio(0);
        __builtin_amdgcn_sched_barrier(0);
        __builtin_amdgcn_s_barrier();
        __builtin_amdgcn_sched_barrier(0);

        // ---- phase 1: read B(j4..7); stage B of tile t+3; counted vmcnt; MFMA j4..7 ----
#pragma unroll
        for (int j = 0; j < 4; ++j)
            bf1[j] = *(const bf16x8*)&bsx[boff + (j + 4) * 16 * BK];
        if (t + 3 < NT)
            stage2(Bg, (t + 3) * BK, &Bs[((t + 3) & 3) * SLOT_E], tid);
        // ensure tile t+1 resident; keep tiles t+2, t+3 in flight (T4: never drain to 0)
        if (t < NT - 3)       asm volatile("s_waitcnt vmcnt(8)" ::: "memory");
        else if (t == NT - 3) asm volatile("s_waitcnt vmcnt(4)" ::: "memory");
        else                  asm volatile("s_waitcnt vmcnt(0)" ::: "memory");
        __builtin_amdgcn_s_barrier();
        __builtin_amdgcn_sched_barrier(0);
        __builtin_amdgcn_s_setprio(1);
#pragma unroll
        for (int i = 0; i < 4; ++i)
#pragma unroll
            for (int j = 0; j < 4; ++j)
                acc[i][j + 4] = __builtin_amdgcn_mfma_f32_16x16x32_bf16(af[i], bf1[j], acc[i][j + 4], 0, 0, 0);
        __builtin_amdgcn_s_setprio(0);
        __builtin_amdgcn_sched_barrier(0);
        __builtin_amdgcn_s_barrier();
        __builtin_amdgcn_sched_barrier(0);
    }

    // ---- epilogue: tile-uniform output region (BN=256 divides D_IN) ----
    int gm0 = bm * 256 + wr * 64 + lhi * 4;
    int col0 = (bn & 7) * 256 + wc * 128 + l15;   // column within 2048-wide output
    int region = bn >> 3;                         // 0: dt, 1: b, 2: c
    if (region == 0) {
#pragma unroll
        for (int j = 0; j < 8; ++j) {
            int col = col0 + j * 16;
            float bias = bdt[col];
#pragma unroll
            for (int i = 0; i < 4; ++i)
#pragma unroll
                for (int r = 0; r < 4; ++r)
                    dtp[(size_t)(gm0 + i * 16 + r) * D_IN + col] =
                        softplus_f(acc[i][j][r] + bias) + 1e-4f;
        }
    } else if (region == 1) {
#pragma unroll
        for (int j = 0; j < 8; ++j) {
            int col = col0 + j * 16;
            float bias = bbv[col];
#pragma unroll
            for (int i = 0; i < 4; ++i)
#pragma unroll
                for (int r = 0; r < 4; ++r)
                    btp[(size_t)(gm0 + i * 16 + r) * D_IN + col] = f2bf(acc[i][j][r] + bias);
        }
    } else {
#pragma unroll
        for (int j = 0; j < 8; ++j) {
            int col = col0 + j * 16;
            float bias = bcv[col];
#pragma unroll
            for (int i = 0; i < 4; ++i)
#pragma unroll
                for (int r = 0; r < 4; ++r)
                    ctp[(size_t)(gm0 + i * 16 + r) * D_IN + col] = f2bf(acc[i][j][r] + bias);
        }
    }
}

// ================= chunked scan, lane = d =================
__device__ __forceinline__ void loadA4(const unsigned short* __restrict__ ub,
                                       const float* __restrict__ dtp,
                                       const unsigned short* __restrict__ btp,
                                       size_t base, int l0,
                                       float (&T)[4], float (&U)[4], float (&Bv)[4]) {
#pragma unroll
    for (int i = 0; i < 4; ++i) {
        size_t off = base + (size_t)(l0 + i) * D_IN;
        T[i] = dtp[off];
        U[i] = bf2f(ub[off]);
        Bv[i] = bf2f(btp[off]);
    }
}

__device__ __forceinline__ void compA4(float (&x)[16], float& sdt,
                                       const float (&A2)[16], const float (&Bb)[16],
                                       const float (&T)[4], const float (&U)[4],
                                       const float (&Bv)[4]) {
#pragma unroll
    for (int i = 0; i < 4; ++i) {
        float dtv = T[i];
        float s = dtv * Bv[i] * U[i];
        sdt += dtv;
#pragma unroll
        for (int n = 0; n < 16; ++n)
            x[n] = fmaf(exp2f(A2[n] * dtv), x[n], s * Bb[n]);
    }
}

__global__ __launch_bounds__(256) void k_scanA(const unsigned short* __restrict__ ub,
                                               const float* __restrict__ dtp,
                                               const unsigned short* __restrict__ btp,
                                               const float* __restrict__ a_raw,
                                               const float* __restrict__ Bbp,
                                               float* __restrict__ localx,
                                               float* __restrict__ sumdt) {
    int tid = threadIdx.x;
    int d = blockIdx.x * 256 + tid;
    int c = blockIdx.y, b = blockIdx.z;
    const float L2E = 1.4426950408889634f;

    float A2[16], Bb[16];
#pragma unroll
    for (int n = 0; n < 16; n += 4) {
        f32x4 a = *(const f32x4*)(a_raw + d * STATE_N + n);
        f32x4 bv = *(const f32x4*)(Bbp + d * STATE_N + n);
#pragma unroll
        for (int j = 0; j < 4; ++j) {
            A2[n + j] = -softplus_f(a[j]) * L2E;
            Bb[n + j] = bv[j];
        }
    }

    size_t base = ((size_t)b * SEQ_L + (size_t)c * LC) * D_IN + d;
    float x[16];
#pragma unroll
    for (int n = 0; n < 16; ++n) x[n] = 0.f;
    float sdt = 0.f;

    float tA[4], uA[4], bA[4], tB[4], uB[4], bB[4];
    loadA4(ub, dtp, btp, base, 0, tA, uA, bA);
    for (int l0 = 0; l0 < LC; l0 += 8) {
        loadA4(ub, dtp, btp, base, l0 + 4, tB, uB, bB);
        compA4(x, sdt, A2, Bb, tA, uA, bA);
        if (l0 + 8 < LC)
            loadA4(ub, dtp, btp, base, l0 + 8, tA, uA, bA);
        compA4(x, sdt, A2, Bb, tB, uB, bB);
    }

    size_t sb = (size_t)c * BDN + ((size_t)b * D_IN + d) * STATE_N;
#pragma unroll
    for (int n = 0; n < 16; n += 4) {
        f32x4 v; v[0] = x[n]; v[1] = x[n + 1]; v[2] = x[n + 2]; v[3] = x[n + 3];
        *(f32x4*)(localx + sb + n) = v;
    }
    sumdt[(size_t)c * BD + (size_t)b * D_IN + d] = sdt;
}

// Pass B: combine chunk summaries -> per-chunk start states + carry.
__global__ __launch_bounds__(256) void k_scanB(const float* __restrict__ localx,
                                               const float* __restrict__ sumdt,
                                               const float* __restrict__ a_raw,
                                               float* __restrict__ x0,
                                               float* __restrict__ carry) {
    int gid = blockIdx.x * 256 + threadIdx.x;   // = (b*D_IN + d)*16 + n
    int n = gid & 15;
    int d = (gid >> 4) & (D_IN - 1);
    int bd = gid >> 4;
    float A2 = -softplus_f(a_raw[d * STATE_N + n]) * 1.4426950408889634f;
    float x = 0.f;
    for (int c = 0; c < NCHUNK; ++c) {
        x0[(size_t)c * BDN + gid] = x;
        float sdt = sumdt[(size_t)c * BD + bd];
        x = fmaf(exp2f(A2 * sdt), x, localx[(size_t)c * BDN + gid]);
    }
    carry[gid] = x;
}

// Pass C: re-scan each chunk from its true start state, emit y.
__device__ __forceinline__ void loadC4(const unsigned short* __restrict__ ub,
                                       const float* __restrict__ dtp,
                                       const unsigned short* __restrict__ btp,
                                       const unsigned short* __restrict__ ctp,
                                       size_t base, int l0,
                                       float (&T)[4], float (&U)[4],
                                       float (&Bv)[4], float (&Cv)[4]) {
#pragma unroll
    for (int i = 0; i < 4; ++i) {
        size_t off = base + (size_t)(l0 + i) * D_IN;
        T[i] = dtp[off];
        U[i] = bf2f(ub[off]);
        Bv[i] = bf2f(btp[off]);
        Cv[i] = bf2f(ctp[off]);
    }
}

__device__ __forceinline__ void compC4(float (&x)[16],
                                       const float (&A2)[16], const float (&Bb)[16],
                                       const float (&Cb)[16], float Dd,
                                       float* __restrict__ y, size_t base, int l0,
                                       const float (&T)[4], const float (&U)[4],
                                       const float (&Bv)[4], const float (&Cv)[4]) {
#pragma unroll
    for (int i = 0; i < 4; ++i) {
        float dtv = T[i], uv = U[i];
        float s = dtv * Bv[i] * uv;
        float y0 = 0.f, y1 = 0.f, y2 = 0.f, y3 = 0.f;
#pragma unroll
        for (int n = 0; n < 16; n += 4) {
            x[n]     = fmaf(exp2f(A2[n] * dtv),     x[n],     s * Bb[n]);
            y0 = fmaf(Cb[n], x[n], y0);
            x[n + 1] = fmaf(exp2f(A2[n + 1] * dtv), x[n + 1], s * Bb[n + 1]);
            y1 = fmaf(Cb[n + 1], x[n + 1], y1);
            x[n + 2] = fmaf(exp2f(A2[n + 2] * dtv), x[n + 2], s * Bb[n + 2]);
            y2 = fmaf(Cb[n + 2], x[n + 2], y2);
            x[n + 3] = fmaf(exp2f(A2[n + 3] * dtv), x[n + 3], s * Bb[n + 3]);
            y3 = fmaf(Cb[n + 3], x[n + 3], y3);
        }
        y[base + (size_t)(l0 + i) * D_IN] = fmaf(Dd, uv, Cv[i] * ((y0 + y1) + (y2 + y3)));
    }
}

__global__ __launch_bounds__(256) void k_scanC(const unsigned short* __restrict__ ub,
                                               const float* __restrict__ dtp,
                                               const unsigned short* __restrict__ btp,
                                               const unsigned short* __restrict__ ctp,
                                               const float* __restrict__ a_raw,
                                               const float* __restrict__ Bbp,
                                               const float* __restrict__ Cbp,
                                               const float* __restrict__ Dv,
                                               const float* __restrict__ x0,
                                               float* __restrict__ y) {
    int tid = threadIdx.x;
    int d = blockIdx.x * 256 + tid;
    int c = blockIdx.y, b = blockIdx.z;
    const float L2E = 1.4426950408889634f;

    float A2[16], Bb[16], Cb[16];
#pragma unroll
    for (int n = 0; n < 16; n += 4) {
        f32x4 a = *(const f32x4*)(a_raw + d * STATE_N + n);
        f32x4 bv = *(const f32x4*)(Bbp + d * STATE_N + n);
        f32x4 cv = *(const f32x4*)(Cbp + d * STATE_N + n);
#pragma unroll
        for (int j = 0; j < 4; ++j) {
            A2[n + j] = -softplus_f(a[j]) * L2E;
            Bb[n + j] = bv[j];
            Cb[n + j] = cv[j];
        }
    }
    float Dd = Dv[d];

    float x[16];
    size_t xb = (size_t)c * BDN + ((size_t)b * D_IN + d) * STATE_N;
#pragma unroll
    for (int n = 0; n < 16; n += 4) {
        f32x4 v = *(const f32x4*)(x0 + xb + n);
        x[n] = v[0]; x[n + 1] = v[1]; x[n + 2] = v[2]; x[n + 3] = v[3];
    }

    size_t base = ((size_t)b * SEQ_L + (size_t)c * LC) * D_IN + d;
    float tA[4], uA[4], bA[4], cA[4], tB[4], uB[4], bB[4], cB[4];
    loadC4(ub, dtp, btp, ctp, base, 0, tA, uA, bA, cA);
    for (int l0 = 0; l0 < LC; l0 += 8) {
        loadC4(ub, dtp, btp, ctp, base, l0 + 4, tB, uB, bB, cB);
        compC4(x, A2, Bb, Cb, Dd, y, base, l0, tA, uA, bA, cA);
        if (l0 + 8 < LC)
            loadC4(ub, dtp, btp, ctp, base, l0 + 8, tA, uA, bA, cA);
        compC4(x, A2, Bb, Cb, Dd, y, base, l0 + 4, tB, uB, bB, cB);
    }
}

// ---------------- launch ----------------
extern "C" void kernel_launch(void* const* d_in, const int* in_sizes, int n_in,
                              void* d_out, int out_size, void* d_ws, size_t ws_size,
                              hipStream_t stream) {
    const float* u     = (const float*)d_in[0];
    const float* Wdt   = (const float*)d_in[1];
    const float* bdt   = (const float*)d_in[2];
    const float* Wb    = (const float*)d_in[3];
    const float* bb    = (const float*)d_in[4];
    const float* Wc    = (const float*)d_in[5];
    const float* bc    = (const float*)d_in[6];
    const float* a_raw = (const float*)d_in[7];
    const float* Bbp   = (const float*)d_in[8];
    const float* Cbp   = (const float*)d_in[9];
    const float* Dv    = (const float*)d_in[10];

    float* out = (float*)d_out;
    float* carry = out;                                      // (B, d, N)
    float* y = out + (size_t)BATCH * D_IN * STATE_N;         // (B, L, d)

    const size_t Mel = (size_t)M_TOT * D_IN;                 // 33.5M elements
    char* ws = (char*)d_ws;
    unsigned short* ub  = (unsigned short*)ws;                          // Mel*2
    unsigned short* Btb = (unsigned short*)(ws + Mel * 2);              // NCAT*D_IN*2
    char* p = ws + Mel * 2 + (size_t)NCAT * D_IN * 2;
    float* dtp = (float*)p;                                             // Mel*4
    unsigned short* btp = (unsigned short*)(p + Mel * 4);               // Mel*2
    unsigned short* ctp = (unsigned short*)(p + Mel * 4 + Mel * 2);     // Mel*2
    char* q = p + Mel * 4 + Mel * 2 + Mel * 2;
    float* localx = (float*)q;                                          // NCHUNK*BDN*4
    float* x0v    = (float*)(q + (size_t)NCHUNK * BDN * 4);             // NCHUNK*BDN*4
    float* sumdt  = (float*)(q + (size_t)NCHUNK * BDN * 8);             // NCHUNK*BD*4

    k_cvt_u<<<dim3((M_TOT * D_IN) / (256 * 8)), dim3(256), 0, stream>>>(u, ub);
    k_transpose<<<dim3(NCAT / 32, D_IN / 32), dim3(32, 8), 0, stream>>>(Wdt, Wb, Wc, Btb);
    k_gemm<<<dim3((M_TOT / 256) * (NCAT / 256)), dim3(512), 0, stream>>>(ub, Btb, bdt, bb, bc,
                                                                         dtp, btp, ctp);
    k_scanA<<<dim3(D_IN / 256, NCHUNK, BATCH), dim3(256), 0, stream>>>(ub, dtp, btp, a_raw,
                                                                       Bbp, localx, sumdt);
    k_scanB<<<dim3(BDN / 256), dim3(256), 0, stream>>>(localx, sumdt, a_raw, x0v, carry);
    k_scanC<<<dim3(D_IN / 256, NCHUNK, BATCH), dim3(256), 0, stream>>>(ub, dtp, btp, ctp,
                                                                       a_raw, Bbp, Cbp, Dv,
                                                                       x0v, y);
}